// Round 1
// baseline (258.875 us; speedup 1.0000x reference)
//
#include <hip/hip_runtime.h>
#include <stdint.h>

typedef __attribute__((ext_vector_type(8))) short short8;   // 8 bf16 (4 VGPRs)
typedef __attribute__((ext_vector_type(4))) float f32x4;

#define LDS_AS __attribute__((address_space(3)))
#define GLOB_AS __attribute__((address_space(1)))

__device__ __forceinline__ void gload_lds16(const void* g, void* l) {
    __builtin_amdgcn_global_load_lds((const GLOB_AS uint32_t*)g,
                                     (LDS_AS uint32_t*)l, 16, 0, 0);
}

__device__ __forceinline__ unsigned short f2bf(float f) {
    uint32_t u = __builtin_bit_cast(uint32_t, f);
    u += 0x7fffu + ((u >> 16) & 1u);
    return (unsigned short)(u >> 16);
}
__device__ __forceinline__ float bf2f(unsigned short u) {
    uint32_t v = ((uint32_t)u) << 16;
    return __builtin_bit_cast(float, v);
}

// ---------------- fp32 -> bf16 convert ----------------
__global__ void cvt_kernel(const float* __restrict__ src,
                           unsigned short* __restrict__ dst, int n) {
    int i = (blockIdx.x * blockDim.x + threadIdx.x) * 4;
    if (i < n) {
        float4 v = *(const float4*)(src + i);
        ushort4 o;
        o.x = f2bf(v.x); o.y = f2bf(v.y); o.z = f2bf(v.z); o.w = f2bf(v.w);
        *(ushort4*)(dst + i) = o;
    }
}

// ---------------- rope tables: cos/sin (2048 x 32) ----------------
__global__ void rope_tables(float* __restrict__ cosT, float* __restrict__ sinT) {
    int tid = blockIdx.x * blockDim.x + threadIdx.x;  // 65536
    int t = tid >> 5, i = tid & 31;
    float f = (i < 16) ? exp2f(-10.0f * (float)i / 15.0f) : 0.0f;
    float th = (float)t * f;
    cosT[tid] = cosf(th);
    sinT[tid] = sinf(th);
}

// ---------------- GEMM C[m,n] = sum_k A[m,k]*B[n,k], bf16 in fp32 acc ----
// MODE 1: qkv epilogue (split q/k/v per head; v lerped with v1 -> fp32 d_out)
// MODE 2: proj epilogue (fp32 + bias)
template <int MODE>
__global__ __launch_bounds__(256, 2) void gemm_bt(
    const unsigned short* __restrict__ A, const unsigned short* __restrict__ B,
    int K,
    unsigned short* __restrict__ qbuf, unsigned short* __restrict__ kbuf,
    float* __restrict__ vout, const float* __restrict__ v1,
    const float* __restrict__ lambp,
    float* __restrict__ y, const float* __restrict__ bias)
{
    __shared__ unsigned short As[128 * 32];
    __shared__ unsigned short Bs[128 * 32];
    const int tid = threadIdx.x;
    const int lane = tid & 63, w = tid >> 6;
    const int wr = w >> 1, wc = w & 1;
    const int lr = lane & 15, lh = lane >> 4;
    const long m0 = (long)blockIdx.x * 128;
    const long n0 = (long)blockIdx.y * 128;

    f32x4 acc[4][4] = {};

    for (int k0 = 0; k0 < K; k0 += 32) {
        __syncthreads();
        for (int c = 0; c < 2; ++c) {
            int chunk = w + c * 4;                 // wave-uniform
            int o = chunk * 1024 + lane * 16;      // byte offset within tile
            int row = o >> 6, colb = o & 63;
            gload_lds16((const char*)A + ((m0 + row) * K + k0) * 2 + colb,
                        (char*)As + chunk * 1024);
            gload_lds16((const char*)B + ((n0 + row) * K + k0) * 2 + colb,
                        (char*)Bs + chunk * 1024);
        }
        __syncthreads();
        short8 a[4], b[4];
        #pragma unroll
        for (int i = 0; i < 4; ++i)
            a[i] = *(const short8*)&As[(wr * 64 + i * 16 + lr) * 32 + lh * 8];
        #pragma unroll
        for (int i = 0; i < 4; ++i)
            b[i] = *(const short8*)&Bs[(wc * 64 + i * 16 + lr) * 32 + lh * 8];
        #pragma unroll
        for (int i = 0; i < 4; ++i)
            #pragma unroll
            for (int j = 0; j < 4; ++j)
                acc[i][j] = __builtin_amdgcn_mfma_f32_16x16x32_bf16(
                    a[i], b[j], acc[i][j], 0, 0, 0);
    }

    float lam = 0.f;
    if constexpr (MODE == 1) lam = lambp[0];

    #pragma unroll
    for (int i = 0; i < 4; ++i)
    #pragma unroll
    for (int j = 0; j < 4; ++j)
    #pragma unroll
    for (int r = 0; r < 4; ++r) {
        long m = m0 + wr * 64 + i * 16 + lh * 4 + r;
        long n = n0 + wc * 64 + j * 16 + lr;
        float v = acc[i][j][r];
        if constexpr (MODE == 1) {
            int kk = (int)(n >> 10);
            int rem = (int)(n & 1023);
            int h = rem >> 6, d = rem & 63;
            long b_ = m >> 11, t = m & 2047;
            size_t idx = (((size_t)(b_ * 16 + h)) * 2048 + t) * 64 + d;
            if (kk == 0) qbuf[idx] = f2bf(v);
            else if (kk == 1) kbuf[idx] = f2bf(v);
            else {
                float vv = v1[(size_t)m * 1024 + rem];
                vout[idx] = (1.0f - lam) * v + lam * vv;
            }
        } else {
            y[(size_t)m * 1024 + n] = v + bias[n];
        }
    }
}

// ---------------- RMS-norm + rotary, in place on (B,H,T,64) bf16 ----------
__global__ __launch_bounds__(256) void normrope_kernel(
    unsigned short* __restrict__ qbuf, unsigned short* __restrict__ kbuf,
    const float* __restrict__ cosT, const float* __restrict__ sinT)
{
    int w = threadIdx.x >> 6, lane = threadIdx.x & 63;
    long rid = (long)blockIdx.x * 4 + w;          // 0 .. 262143
    unsigned short* buf = (rid < 131072) ? qbuf : kbuf;
    long r = rid & 131071;
    int t = (int)(r & 2047);
    float x = bf2f(buf[r * 64 + lane]);
    float ss = x * x;
    #pragma unroll
    for (int m = 1; m < 64; m <<= 1) ss += __shfl_xor(ss, m);
    float inv = rsqrtf(ss * (1.0f / 64.0f) + 1e-6f);
    float xn = x * inv;
    float partner = __shfl_xor(xn, 32);
    int d = lane & 31;
    float c = cosT[t * 32 + d], s = sinT[t * 32 + d];
    float yv = (lane < 32) ? (xn * c + partner * s) : (xn * c - partner * s);
    buf[r * 64 + lane] = f2bf(yv);
}

// ---------------- flash attention, sliding window ----------------
// block = 4 waves; block handles one (b,h) and 64 q rows; wave = 16 q rows.
__global__ __launch_bounds__(256, 2) void attn_kernel(
    const unsigned short* __restrict__ qn, const unsigned short* __restrict__ kn,
    const float* __restrict__ vout, unsigned short* __restrict__ attn_out,
    const int* __restrict__ winp)
{
    __shared__ unsigned short Vt[64][72];        // V^T tile: [d][key]
    __shared__ unsigned short Pl[4][16][72];     // per-wave P: [qrow][key]
    const int tid = threadIdx.x, lane = tid & 63, w = tid >> 6;
    const int lr = lane & 15, lh = lane >> 4;
    const int bh = blockIdx.x;                   // 0..63
    const int qt = blockIdx.y;                   // 0..31
    const int t0 = qt * 64;
    const int win = winp[0];
    const int qrow = t0 + w * 16;

    short8 qf[2];
    #pragma unroll
    for (int ks = 0; ks < 2; ++ks)
        qf[ks] = *(const short8*)&qn[((size_t)bh * 2048 + qrow + lr) * 64 + ks * 32 + lh * 8];

    f32x4 oacc[4] = {};
    float mrow[4], lrow[4];
    #pragma unroll
    for (int r = 0; r < 4; ++r) { mrow[r] = -1e30f; lrow[r] = 0.f; }

    int kvt0 = max(0, t0 - win + 1) >> 6;
    for (int kvt = kvt0; kvt <= qt; ++kvt) {
        int j0 = kvt * 64;
        __syncthreads();
        {   // stage V transposed (fp32 value -> bf16 LDS)
            int rr = tid >> 2, c0 = (tid & 3) * 16;
            const float* src = &vout[((size_t)bh * 2048 + j0 + rr) * 64 + c0];
            #pragma unroll
            for (int jj = 0; jj < 4; ++jj) {
                float4 f = *(const float4*)(src + jj * 4);
                Vt[c0 + jj * 4 + 0][rr] = f2bf(f.x);
                Vt[c0 + jj * 4 + 1][rr] = f2bf(f.y);
                Vt[c0 + jj * 4 + 2][rr] = f2bf(f.z);
                Vt[c0 + jj * 4 + 3][rr] = f2bf(f.w);
            }
        }
        __syncthreads();

        // S = Q K^T
        float sv[4][4];
        #pragma unroll
        for (int kt = 0; kt < 4; ++kt) {
            f32x4 s = {};
            #pragma unroll
            for (int ks = 0; ks < 2; ++ks) {
                short8 kf = *(const short8*)&kn[((size_t)bh * 2048 + j0 + kt * 16 + lr) * 64 + ks * 32 + lh * 8];
                s = __builtin_amdgcn_mfma_f32_16x16x32_bf16(qf[ks], kf, s, 0, 0, 0);
            }
            #pragma unroll
            for (int r = 0; r < 4; ++r) {
                int qi = qrow + lh * 4 + r;
                int ji = j0 + kt * 16 + lr;
                bool ok = (ji <= qi) && (qi - ji < win);
                sv[kt][r] = ok ? s[r] * 0.125f : -1e30f;
            }
        }

        // online softmax (rows live on lanes sharing lh; reduce across lr)
        float pn[4][4];
        #pragma unroll
        for (int r = 0; r < 4; ++r) {
            float tm = fmaxf(fmaxf(sv[0][r], sv[1][r]), fmaxf(sv[2][r], sv[3][r]));
            #pragma unroll
            for (int m = 1; m < 16; m <<= 1) tm = fmaxf(tm, __shfl_xor(tm, m));
            float nm = fmaxf(mrow[r], tm);
            float alpha = __expf(mrow[r] - nm);
            float ps = 0.f;
            #pragma unroll
            for (int kt = 0; kt < 4; ++kt) {
                float p = __expf(sv[kt][r] - nm);
                pn[kt][r] = p; ps += p;
            }
            #pragma unroll
            for (int m = 1; m < 16; m <<= 1) ps += __shfl_xor(ps, m);
            lrow[r] = lrow[r] * alpha + ps;
            mrow[r] = nm;
            #pragma unroll
            for (int dt = 0; dt < 4; ++dt) oacc[dt][r] *= alpha;
        }

        // P -> per-wave LDS (transpose to A-fragment layout)
        #pragma unroll
        for (int kt = 0; kt < 4; ++kt)
            #pragma unroll
            for (int r = 0; r < 4; ++r)
                Pl[w][lh * 4 + r][kt * 16 + lr] = f2bf(pn[kt][r]);

        short8 pf[2];
        #pragma unroll
        for (int ks = 0; ks < 2; ++ks)
            pf[ks] = *(const short8*)&Pl[w][lr][ks * 32 + lh * 8];
        #pragma unroll
        for (int dt = 0; dt < 4; ++dt)
            #pragma unroll
            for (int ks = 0; ks < 2; ++ks) {
                short8 vf = *(const short8*)&Vt[dt * 16 + lr][ks * 32 + lh * 8];
                oacc[dt] = __builtin_amdgcn_mfma_f32_16x16x32_bf16(pf[ks], vf, oacc[dt], 0, 0, 0);
            }
    }

    // write attention output (B,T,C) bf16
    int b = bh >> 4, h = bh & 15;
    #pragma unroll
    for (int dt = 0; dt < 4; ++dt)
        #pragma unroll
        for (int r = 0; r < 4; ++r) {
            int t = qrow + lh * 4 + r;
            float o = oacc[dt][r] / lrow[r];
            attn_out[((size_t)b * 2048 + t) * 1024 + h * 64 + dt * 16 + lr] = f2bf(o);
        }
}

extern "C" void kernel_launch(void* const* d_in, const int* in_sizes, int n_in,
                              void* d_out, int out_size, void* d_ws, size_t ws_size,
                              hipStream_t stream) {
    const float* x    = (const float*)d_in[0];
    const float* v1   = (const float*)d_in[1];
    const float* qkvw = (const float*)d_in[2];
    const float* cpw  = (const float*)d_in[3];
    const float* cpb  = (const float*)d_in[4];
    const float* lamb = (const float*)d_in[5];
    const int*   winp = (const int*)d_in[6];

    float* y    = (float*)d_out;
    float* vout = y + (size_t)8192 * 1024;   // value output (B,H,T,64) fp32

    char* ws = (char*)d_ws;
    unsigned short* xb   = (unsigned short*)(ws);                 // 16MB (reused as attn_out)
    unsigned short* Wb   = (unsigned short*)(ws + (16u << 20));   // 6MB
    unsigned short* Wp   = (unsigned short*)(ws + (22u << 20));   // 2MB
    unsigned short* qbuf = (unsigned short*)(ws + (24u << 20));   // 16MB
    unsigned short* kbuf = (unsigned short*)(ws + (40u << 20));   // 16MB
    float* cosT = (float*)(ws + (56u << 20));                     // 256KB
    float* sinT = (float*)(ws + (56u << 20) + (256u << 10));      // 256KB

    cvt_kernel<<<8388608 / 1024, 256, 0, stream>>>(x, xb, 8388608);
    cvt_kernel<<<3145728 / 1024, 256, 0, stream>>>(qkvw, Wb, 3145728);
    cvt_kernel<<<1048576 / 1024, 256, 0, stream>>>(cpw, Wp, 1048576);
    rope_tables<<<65536 / 256, 256, 0, stream>>>(cosT, sinT);

    gemm_bt<1><<<dim3(64, 24), 256, 0, stream>>>(xb, Wb, 1024,
        qbuf, kbuf, vout, v1, lamb, nullptr, nullptr);

    normrope_kernel<<<65536, 256, 0, stream>>>(qbuf, kbuf, cosT, sinT);

    attn_kernel<<<dim3(64, 32), 256, 0, stream>>>(qbuf, kbuf, vout, xb, winp);

    gemm_bt<2><<<dim3(64, 8), 256, 0, stream>>>(xb, Wp, 1024,
        nullptr, nullptr, nullptr, nullptr, nullptr, y, cpb);
}